// Round 1
// baseline (7126.997 us; speedup 1.0000x reference)
//
#include <hip/hip_runtime.h>

#define F 128

// W_rel[r][k][o] = sum_b comp[r][b] * basis[b][k][o]
__global__ void mix_kernel(const float* __restrict__ comp, const float* __restrict__ basis,
                           float* __restrict__ Wrel, int R, int B) {
    int idx = blockIdx.x * blockDim.x + threadIdx.x;
    int total = R * F * F;
    if (idx >= total) return;
    int r = idx / (F * F);
    int io = idx % (F * F);
    float acc = 0.f;
    for (int b = 0; b < B; ++b) acc += comp[r * B + b] * basis[b * F * F + io];
    Wrel[idx] = acc;
}

// pre[n][o] = sum_k x[n][k] * W[k][o]; one block computes 128 rows x 128 cols.
// LDS XOR-swizzles: xs swizzled along k by row-group (a-reads conflict-free),
// ws swizzled along o by col-group (b-reads 2-way, ~free).
__global__ __launch_bounds__(256) void gemm128(const float* __restrict__ x,
                                               const float* __restrict__ W,
                                               float* __restrict__ pre, int n) {
    __shared__ float xs[128][128];
    __shared__ float ws[128][128];
    const int t = threadIdx.x;
    const int row0 = blockIdx.x * 128;

    // stage W (64KB) swizzled: element (k,c) at ws[k][c ^ (((c>>5)&1)<<2)]
    for (int i4 = t; i4 < 128 * 32; i4 += 256) {
        int k = i4 >> 5;
        int c = (i4 & 31) << 2;
        int sc = c ^ (((c >> 5) & 1) << 2);
        *(float4*)&ws[k][sc] = *(const float4*)&W[k * F + c];
    }
    // stage x tile swizzled: element (r,k) at xs[r][k ^ (((r>>3)&3)<<2)]
    for (int i4 = t; i4 < 128 * 32; i4 += 256) {
        int r = i4 >> 5;
        int c = (i4 & 31) << 2;
        int gr = row0 + r;
        float4 v = make_float4(0.f, 0.f, 0.f, 0.f);
        if (gr < n) v = *(const float4*)&x[gr * F + c];
        int sc = c ^ (((r >> 3) & 3) << 2);
        *(float4*)&xs[r][sc] = v;
    }
    __syncthreads();

    const int tr = (t >> 4) << 3;   // 0..120 step 8
    const int tc = (t & 15) << 3;   // 0..120 step 8
    const int xsw = ((tr >> 3) & 3) << 2;
    const int wsw = ((tc >> 5) & 1) << 2;

    float acc[8][8] = {};
    for (int k0 = 0; k0 < F; k0 += 4) {
        float4 a4[8];
#pragma unroll
        for (int i = 0; i < 8; ++i)
            a4[i] = *(float4*)&xs[tr + i][k0 ^ xsw];
        float4 bA[4], bB[4];
#pragma unroll
        for (int kk = 0; kk < 4; ++kk) {
            bA[kk] = *(float4*)&ws[k0 + kk][tc ^ wsw];
            bB[kk] = *(float4*)&ws[k0 + kk][(tc + 4) ^ wsw];
        }
#pragma unroll
        for (int kk = 0; kk < 4; ++kk) {
            float bv[8] = {bA[kk].x, bA[kk].y, bA[kk].z, bA[kk].w,
                           bB[kk].x, bB[kk].y, bB[kk].z, bB[kk].w};
#pragma unroll
            for (int i = 0; i < 8; ++i) {
                float av = (kk == 0) ? a4[i].x : (kk == 1) ? a4[i].y
                          : (kk == 2) ? a4[i].z : a4[i].w;
#pragma unroll
                for (int j = 0; j < 8; ++j) acc[i][j] += av * bv[j];
            }
        }
    }

#pragma unroll
    for (int i = 0; i < 8; ++i) {
        int gr = row0 + tr + i;
        if (gr < n) {
            *(float4*)&pre[gr * F + tc] =
                make_float4(acc[i][0], acc[i][1], acc[i][2], acc[i][3]);
            *(float4*)&pre[gr * F + tc + 4] =
                make_float4(acc[i][4], acc[i][5], acc[i][6], acc[i][7]);
        }
    }
}

// 32 lanes per edge; each lane handles 4 consecutive features.
__global__ __launch_bounds__(256) void scatter_kernel(const float* __restrict__ pre,
                                                      const float* __restrict__ vals,
                                                      const int* __restrict__ src,
                                                      const int* __restrict__ dst,
                                                      float* __restrict__ out, int E) {
    int gtid = blockIdx.x * 256 + threadIdx.x;
    int e = gtid >> 5;
    if (e >= E) return;
    int lane = gtid & 31;
    int s = src[e], d = dst[e];
    float v = vals[e];
    float4 p = *(const float4*)&pre[s * F + lane * 4];
    float* o = &out[d * F + lane * 4];
    atomicAdd(o + 0, v * p.x);
    atomicAdd(o + 1, v * p.y);
    atomicAdd(o + 2, v * p.z);
    atomicAdd(o + 3, v * p.w);
}

__global__ void relu_kernel(float* __restrict__ out, int total4) {
    int i = blockIdx.x * blockDim.x + threadIdx.x;
    if (i >= total4) return;
    float4 v = ((float4*)out)[i];
    v.x = fmaxf(v.x, 0.f);
    v.y = fmaxf(v.y, 0.f);
    v.z = fmaxf(v.z, 0.f);
    v.w = fmaxf(v.w, 0.f);
    ((float4*)out)[i] = v;
}

extern "C" void kernel_launch(void* const* d_in, const int* in_sizes, int n_in,
                              void* d_out, int out_size, void* d_ws, size_t ws_size,
                              hipStream_t stream) {
    const float* x  = (const float*)d_in[0];
    const float* Wb = (const float*)d_in[1];
    const float* Wc = (const float*)d_in[2];
    const float* ev = (const float*)d_in[3];
    const int*   es = (const int*)d_in[4];
    const int*   ed = (const int*)d_in[5];
    float* out = (float*)d_out;

    const int N = in_sizes[0] / F;           // 50000
    const int B = in_sizes[1] / (F * F);     // 4
    const int R = in_sizes[2] / B;           // 8
    const int E = in_sizes[3] / R;           // 500000

    float* Wrel = (float*)d_ws;                       // R*F*F floats = 512KB
    float* pre  = Wrel + (size_t)R * F * F;           // N*F floats = 25.6MB

    hipMemsetAsync(d_out, 0, (size_t)out_size * sizeof(float), stream);

    mix_kernel<<<(R * F * F + 255) / 256, 256, 0, stream>>>(Wc, Wb, Wrel, R, B);

    const int gblocks = (N + 127) / 128;
    const int sblocks = (E * 32 + 255) / 256;
    for (int r = 0; r < R; ++r) {
        gemm128<<<gblocks, 256, 0, stream>>>(x, Wrel + (size_t)r * F * F, pre, N);
        scatter_kernel<<<sblocks, 256, 0, stream>>>(
            pre, ev + (size_t)r * E, es + (size_t)r * E, ed + (size_t)r * E, out, E);
    }

    relu_kernel<<<(N * F / 4 + 255) / 256, 256, 0, stream>>>(out, N * F / 4);
}

// Round 2
// 1260.217 us; speedup vs baseline: 5.6554x; 5.6554x over previous
//
#include <hip/hip_runtime.h>

#define F 128

// W_rel[r][k][o] = sum_b comp[r][b] * basis[b][k][o]
__global__ void mix_kernel(const float* __restrict__ comp, const float* __restrict__ basis,
                           float* __restrict__ Wrel, int R, int B) {
    int idx = blockIdx.x * blockDim.x + threadIdx.x;
    int total = R * F * F;
    if (idx >= total) return;
    int r = idx / (F * F);
    int io = idx % (F * F);
    float acc = 0.f;
    for (int b = 0; b < B; ++b) acc += comp[r * B + b] * basis[b * F * F + io];
    Wrel[idx] = acc;
}

// pre[n][o] = sum_k x[n][k] * W[k][o]; one block computes 128 rows x 128 cols.
__global__ __launch_bounds__(256) void gemm128(const float* __restrict__ x,
                                               const float* __restrict__ W,
                                               float* __restrict__ pre, int n) {
    __shared__ float xs[128][128];
    __shared__ float ws[128][128];
    const int t = threadIdx.x;
    const int row0 = blockIdx.x * 128;

    for (int i4 = t; i4 < 128 * 32; i4 += 256) {
        int k = i4 >> 5;
        int c = (i4 & 31) << 2;
        int sc = c ^ (((c >> 5) & 1) << 2);
        *(float4*)&ws[k][sc] = *(const float4*)&W[k * F + c];
    }
    for (int i4 = t; i4 < 128 * 32; i4 += 256) {
        int r = i4 >> 5;
        int c = (i4 & 31) << 2;
        int gr = row0 + r;
        float4 v = make_float4(0.f, 0.f, 0.f, 0.f);
        if (gr < n) v = *(const float4*)&x[gr * F + c];
        int sc = c ^ (((r >> 3) & 3) << 2);
        *(float4*)&xs[r][sc] = v;
    }
    __syncthreads();

    const int tr = (t >> 4) << 3;
    const int tc = (t & 15) << 3;
    const int xsw = ((tr >> 3) & 3) << 2;
    const int wsw = ((tc >> 5) & 1) << 2;

    float acc[8][8] = {};
    for (int k0 = 0; k0 < F; k0 += 4) {
        float4 a4[8];
#pragma unroll
        for (int i = 0; i < 8; ++i)
            a4[i] = *(float4*)&xs[tr + i][k0 ^ xsw];
        float4 bA[4], bB[4];
#pragma unroll
        for (int kk = 0; kk < 4; ++kk) {
            bA[kk] = *(float4*)&ws[k0 + kk][tc ^ wsw];
            bB[kk] = *(float4*)&ws[k0 + kk][(tc + 4) ^ wsw];
        }
#pragma unroll
        for (int kk = 0; kk < 4; ++kk) {
            float bv[8] = {bA[kk].x, bA[kk].y, bA[kk].z, bA[kk].w,
                           bB[kk].x, bB[kk].y, bB[kk].z, bB[kk].w};
#pragma unroll
            for (int i = 0; i < 8; ++i) {
                float av = (kk == 0) ? a4[i].x : (kk == 1) ? a4[i].y
                          : (kk == 2) ? a4[i].z : a4[i].w;
#pragma unroll
                for (int j = 0; j < 8; ++j) acc[i][j] += av * bv[j];
            }
        }
    }

#pragma unroll
    for (int i = 0; i < 8; ++i) {
        int gr = row0 + tr + i;
        if (gr < n) {
            *(float4*)&pre[gr * F + tc] =
                make_float4(acc[i][0], acc[i][1], acc[i][2], acc[i][3]);
            *(float4*)&pre[gr * F + tc + 4] =
                make_float4(acc[i][4], acc[i][5], acc[i][6], acc[i][7]);
        }
    }
}

// counts[r][dst]++ over all relations in one pass
__global__ void hist_kernel(const int* __restrict__ ed, int* __restrict__ cnt,
                            int E, int n) {
    int e = blockIdx.x * blockDim.x + threadIdx.x;
    int r = blockIdx.y;
    if (e >= E) return;
    atomicAdd(&cnt[(size_t)r * n + ed[(size_t)r * E + e]], 1);
}

// per-relation exclusive scan: one block per relation, 1024 threads
__global__ __launch_bounds__(1024) void scan_kernel(const int* __restrict__ cnt,
                                                    int* __restrict__ offs,
                                                    int* __restrict__ curs, int n) {
    __shared__ int sums[1024];
    int r = blockIdx.x;
    const int* c = cnt + (size_t)r * n;
    int* o = offs + (size_t)r * (n + 1);
    int* cu = curs + (size_t)r * n;
    int t = threadIdx.x;
    int ch = (n + 1023) / 1024;
    int beg = t * ch;
    int end = min(beg + ch, n);
    if (beg > n) beg = n;
    int s = 0;
    for (int i = beg; i < end; ++i) s += c[i];
    sums[t] = s;
    __syncthreads();
    for (int d = 1; d < 1024; d <<= 1) {
        int v = (t >= d) ? sums[t - d] : 0;
        __syncthreads();
        sums[t] += v;
        __syncthreads();
    }
    int run = (t == 0) ? 0 : sums[t - 1];
    for (int i = beg; i < end; ++i) {
        o[i] = run;
        cu[i] = run;
        run += c[i];
    }
    if (t == 1023) o[n] = sums[1023];
}

// per-relation: place (src,val) into dst-sorted payload via cursor atomics
__global__ void fill_kernel(const int* __restrict__ src, const float* __restrict__ val,
                            const int* __restrict__ dst, int* __restrict__ curs,
                            int2* __restrict__ payload, int E) {
    int e = blockIdx.x * blockDim.x + threadIdx.x;
    if (e >= E) return;
    int d = dst[e];
    int pos = atomicAdd(&curs[d], 1);
    payload[pos] = make_int2(src[e], __float_as_int(val[e]));
}

// one 64-lane wave per dst node: gather pre[src] rows, register-accumulate,
// single non-atomic RMW into out.
__global__ __launch_bounds__(256) void accum_kernel(const float* __restrict__ pre,
                                                    const int2* __restrict__ payload,
                                                    const int* __restrict__ offs,
                                                    float* __restrict__ out, int n) {
    int wave = threadIdx.x >> 6;
    int lane = threadIdx.x & 63;
    int d = blockIdx.x * 4 + wave;
    if (d >= n) return;
    int b = offs[d], e2 = offs[d + 1];
    const float2* pre2 = (const float2*)pre;
    float2 acc = make_float2(0.f, 0.f);
    int j = b;
    for (; j + 1 < e2; j += 2) {
        int2 m0 = payload[j];
        int2 m1 = payload[j + 1];
        float2 p0 = pre2[(size_t)m0.x * 64 + lane];
        float2 p1 = pre2[(size_t)m1.x * 64 + lane];
        float v0 = __int_as_float(m0.y);
        float v1 = __int_as_float(m1.y);
        acc.x += v0 * p0.x + v1 * p1.x;
        acc.y += v0 * p0.y + v1 * p1.y;
    }
    if (j < e2) {
        int2 m = payload[j];
        float v = __int_as_float(m.y);
        float2 p = pre2[(size_t)m.x * 64 + lane];
        acc.x += v * p.x;
        acc.y += v * p.y;
    }
    float2* o = (float2*)out + (size_t)d * 64 + lane;
    float2 cur = *o;
    cur.x += acc.x;
    cur.y += acc.y;
    *o = cur;
}

__global__ void relu_kernel(float* __restrict__ out, int total4) {
    int i = blockIdx.x * blockDim.x + threadIdx.x;
    if (i >= total4) return;
    float4 v = ((float4*)out)[i];
    v.x = fmaxf(v.x, 0.f);
    v.y = fmaxf(v.y, 0.f);
    v.z = fmaxf(v.z, 0.f);
    v.w = fmaxf(v.w, 0.f);
    ((float4*)out)[i] = v;
}

extern "C" void kernel_launch(void* const* d_in, const int* in_sizes, int n_in,
                              void* d_out, int out_size, void* d_ws, size_t ws_size,
                              hipStream_t stream) {
    const float* x  = (const float*)d_in[0];
    const float* Wb = (const float*)d_in[1];
    const float* Wc = (const float*)d_in[2];
    const float* ev = (const float*)d_in[3];
    const int*   es = (const int*)d_in[4];
    const int*   ed = (const int*)d_in[5];
    float* out = (float*)d_out;

    const int N = in_sizes[0] / F;
    const int B = in_sizes[1] / (F * F);
    const int R = in_sizes[2] / B;
    const int E = in_sizes[3] / R;

    // ws layout (16B-aligned chunks)
    char* w = (char*)d_ws;
    float* Wrel = (float*)w;                    w += (size_t)R * F * F * 4;       // 512 KB
    float* pre  = (float*)w;                    w += (size_t)N * F * 4;           // 25.6 MB
    int*   cnt  = (int*)w;                      w += (size_t)R * N * 4;           // 1.6 MB
    int*   offs = (int*)w;                      w += (size_t)R * (N + 1) * 4;     // 1.6 MB
    int*   curs = (int*)w;                      w += (size_t)R * N * 4;           // 1.6 MB
    w = (char*)(((uintptr_t)w + 15) & ~(uintptr_t)15);
    int2*  payload = (int2*)w;                  /* E * 8 B = 4 MB */

    hipMemsetAsync(d_out, 0, (size_t)out_size * sizeof(float), stream);
    hipMemsetAsync(cnt, 0, (size_t)R * N * sizeof(int), stream);

    mix_kernel<<<(R * F * F + 255) / 256, 256, 0, stream>>>(Wc, Wb, Wrel, R, B);

    dim3 hgrid((E + 255) / 256, R);
    hist_kernel<<<hgrid, 256, 0, stream>>>(ed, cnt, E, N);
    scan_kernel<<<R, 1024, 0, stream>>>(cnt, offs, curs, N);

    const int gblocks = (N + 127) / 128;
    const int ablocks = (N + 3) / 4;
    for (int r = 0; r < R; ++r) {
        gemm128<<<gblocks, 256, 0, stream>>>(x, Wrel + (size_t)r * F * F, pre, N);
        fill_kernel<<<(E + 255) / 256, 256, 0, stream>>>(
            es + (size_t)r * E, ev + (size_t)r * E, ed + (size_t)r * E,
            curs + (size_t)r * N, payload, E);
        accum_kernel<<<ablocks, 256, 0, stream>>>(
            pre, payload, offs + (size_t)r * (N + 1), out, N);
    }

    relu_kernel<<<(N * F / 4 + 255) / 256, 256, 0, stream>>>(out, N * F / 4);
}

// Round 3
// 539.934 us; speedup vs baseline: 13.1998x; 2.3340x over previous
//
#include <hip/hip_runtime.h>

#define F 128
#define NB 4
#define NR 8

typedef __attribute__((ext_vector_type(8))) short bf16x8;
typedef __attribute__((ext_vector_type(4))) float f32x4;

__device__ __forceinline__ unsigned f2bf(float f) {  // RNE f32->bf16
    unsigned u = __float_as_uint(f);
    return (u + 0x7FFFu + ((u >> 16) & 1u)) >> 16;
}
__device__ __forceinline__ unsigned f2bf2(float lo, float hi) {
    return f2bf(lo) | (f2bf(hi) << 16);
}
__device__ __forceinline__ float bf2f(unsigned h) {
    return __uint_as_float(h << 16);
}

// x f32 [N*128] -> bf16, 8 elems/thread
__global__ void cvt_x_kernel(const float4* __restrict__ x4, uint4* __restrict__ xb, int total8) {
    int i = blockIdx.x * blockDim.x + threadIdx.x;
    if (i >= total8) return;
    float4 a = x4[(size_t)i * 2], b = x4[(size_t)i * 2 + 1];
    xb[i] = make_uint4(f2bf2(a.x, a.y), f2bf2(a.z, a.w), f2bf2(b.x, b.y), f2bf2(b.z, b.w));
}

// Bt[o][b*128+k] = bf16(W_basis[b][k][o]) : [128][512]
__global__ void cvt_w_kernel(const float* __restrict__ Wb, unsigned short* __restrict__ Bt) {
    int t = blockIdx.x * blockDim.x + threadIdx.x;
    if (t >= F * NB * F) return;
    int o = t >> 9, bk = t & 511, b = bk >> 7, k = bk & 127;
    Bt[t] = (unsigned short)f2bf(Wb[((size_t)b * F + k) * F + o]);
}

// combined histogram over dst; atomic return value doubles as per-edge rank
template <bool RANK>
__global__ void hist_kernel(const int* __restrict__ ed, int* __restrict__ cnt,
                            unsigned short* __restrict__ rank, int E) {
    int e = blockIdx.x * blockDim.x + threadIdx.x;
    if (e >= E) return;
    size_t idx = (size_t)blockIdx.y * E + e;
    int rk = atomicAdd(&cnt[ed[idx]], 1);
    if (RANK) rank[idx] = (unsigned short)rk;
}

__global__ __launch_bounds__(1024) void scan_kernel(const int* __restrict__ cnt, int* __restrict__ offs,
                                                    int* __restrict__ curs, int n) {
    __shared__ int sums[1024];
    int t = threadIdx.x;
    int ch = (n + 1023) >> 10;
    int beg = min(t * ch, n), end = min(beg + ch, n);
    int s = 0;
    for (int i = beg; i < end; ++i) s += cnt[i];
    sums[t] = s;
    __syncthreads();
    for (int d = 1; d < 1024; d <<= 1) {
        int v = (t >= d) ? sums[t - d] : 0;
        __syncthreads();
        sums[t] += v;
        __syncthreads();
    }
    int run = (t == 0) ? 0 : sums[t - 1];
    for (int i = beg; i < end; ++i) {
        offs[i] = run;
        if (curs) curs[i] = run;
        run += cnt[i];
    }
    if (t == 1023) offs[n] = run;
}

// place (src|rel, val) at dst-sorted position
template <bool RANK>
__global__ void fill_kernel(const int* __restrict__ es, const float* __restrict__ ev,
                            const int* __restrict__ ed, const int* __restrict__ offs,
                            const unsigned short* __restrict__ rank, int* __restrict__ curs,
                            int2* __restrict__ payload, int E) {
    int e = blockIdx.x * blockDim.x + threadIdx.x;
    if (e >= E) return;
    int r = blockIdx.y;
    size_t idx = (size_t)r * E + e;
    int d = ed[idx];
    int pos = RANK ? offs[d] + (int)rank[idx] : atomicAdd(&curs[d], 1);
    payload[pos] = make_int2(es[idx] | (r << 24), __float_as_int(ev[idx]));
}

// one wave per dst: gather x rows, accumulate 4 basis-weighted sums in regs,
// write mix[d][b*128 + lane*2 .. +1] as packed bf16.
template <bool XB>
__global__ __launch_bounds__(256) void accum_kernel(const void* __restrict__ xsrc,
                                                    const int2* __restrict__ payload,
                                                    const int* __restrict__ offs,
                                                    const float* __restrict__ comp,
                                                    unsigned* __restrict__ mix,
                                                    int c0, int c1) {
    __shared__ float4 scomp[NR];
    if (threadIdx.x < NR) scomp[threadIdx.x] = ((const float4*)comp)[threadIdx.x];
    __syncthreads();
    int wave = threadIdx.x >> 6, lane = threadIdx.x & 63;
    int d = c0 + blockIdx.x * 4 + wave;
    if (d >= c1) return;
    int jb = offs[d], je = offs[d + 1];
    const unsigned* xb = (const unsigned*)xsrc;
    const float2* xf = (const float2*)xsrc;
    float2 acc0 = {0.f, 0.f}, acc1 = {0.f, 0.f}, acc2 = {0.f, 0.f}, acc3 = {0.f, 0.f};
    int j = jb;
    for (; j + 2 <= je; j += 2) {
        int2 m0 = payload[j], m1 = payload[j + 1];
        unsigned p0 = (unsigned)m0.x, p1 = (unsigned)m1.x;
        int s0 = p0 & 0xFFFFFF, s1 = p1 & 0xFFFFFF;
        float2 x0, x1;
        if (XB) {
            unsigned g0 = xb[(size_t)s0 * 64 + lane];
            unsigned g1 = xb[(size_t)s1 * 64 + lane];
            x0 = make_float2(bf2f(g0 & 0xFFFFu), bf2f(g0 >> 16));
            x1 = make_float2(bf2f(g1 & 0xFFFFu), bf2f(g1 >> 16));
        } else {
            x0 = xf[(size_t)s0 * 64 + lane];
            x1 = xf[(size_t)s1 * 64 + lane];
        }
        float v0 = __int_as_float(m0.y), v1 = __int_as_float(m1.y);
        float4 cw0 = scomp[p0 >> 24], cw1 = scomp[p1 >> 24];
        float w;
        w = v0 * cw0.x; acc0.x += w * x0.x; acc0.y += w * x0.y;
        w = v0 * cw0.y; acc1.x += w * x0.x; acc1.y += w * x0.y;
        w = v0 * cw0.z; acc2.x += w * x0.x; acc2.y += w * x0.y;
        w = v0 * cw0.w; acc3.x += w * x0.x; acc3.y += w * x0.y;
        w = v1 * cw1.x; acc0.x += w * x1.x; acc0.y += w * x1.y;
        w = v1 * cw1.y; acc1.x += w * x1.x; acc1.y += w * x1.y;
        w = v1 * cw1.z; acc2.x += w * x1.x; acc2.y += w * x1.y;
        w = v1 * cw1.w; acc3.x += w * x1.x; acc3.y += w * x1.y;
    }
    if (j < je) {
        int2 m = payload[j];
        unsigned pp = (unsigned)m.x;
        int s = pp & 0xFFFFFF;
        float2 xv;
        if (XB) {
            unsigned g = xb[(size_t)s * 64 + lane];
            xv = make_float2(bf2f(g & 0xFFFFu), bf2f(g >> 16));
        } else {
            xv = xf[(size_t)s * 64 + lane];
        }
        float v = __int_as_float(m.y);
        float4 cw = scomp[pp >> 24];
        float w;
        w = v * cw.x; acc0.x += w * xv.x; acc0.y += w * xv.y;
        w = v * cw.y; acc1.x += w * xv.x; acc1.y += w * xv.y;
        w = v * cw.z; acc2.x += w * xv.x; acc2.y += w * xv.y;
        w = v * cw.w; acc3.x += w * xv.x; acc3.y += w * xv.y;
    }
    unsigned* mrow = mix + (size_t)(d - c0) * 256 + lane;
    mrow[0]   = f2bf2(acc0.x, acc0.y);
    mrow[64]  = f2bf2(acc1.x, acc1.y);
    mrow[128] = f2bf2(acc2.x, acc2.y);
    mrow[192] = f2bf2(acc3.x, acc3.y);
}

// out[gbase+row][o] = relu( sum_K mix[row][K] * Bt[o][K] ), K=512.
// 4 waves, tile 128x128, BK=64, XOR-swizzled LDS, MFMA 16x16x32 bf16.
__global__ __launch_bounds__(256) void gemm_mfma(const unsigned short* __restrict__ mix,
                                                 const unsigned short* __restrict__ Bt,
                                                 float* __restrict__ out,
                                                 int rows, int gbase, int N) {
    __shared__ unsigned short As[128 * 64];
    __shared__ unsigned short Bs[128 * 64];
    const int t = threadIdx.x;
    const int row0 = blockIdx.x * 128;
    const int w = t >> 6, lane = t & 63;
    f32x4 acc[2][8] = {};

    for (int kt = 0; kt < 8; ++kt) {
        __syncthreads();
        for (int u = t; u < 1024; u += 256) {
            int r = u >> 3, c = u & 7;
            int k8 = c * 8;
            int ks = k8 ^ ((r & 7) << 3);
            uint4 av = make_uint4(0, 0, 0, 0);
            if (row0 + r < rows) av = *(const uint4*)&mix[(size_t)(row0 + r) * 512 + kt * 64 + k8];
            *(uint4*)&As[r * 64 + ks] = av;
            uint4 bv = *(const uint4*)&Bt[(size_t)r * 512 + kt * 64 + k8];
            *(uint4*)&Bs[r * 64 + ks] = bv;
        }
        __syncthreads();
#pragma unroll
        for (int ks = 0; ks < 2; ++ks) {
            bf16x8 a[2], b[8];
            const int kbase = ks * 32 + (lane >> 4) * 8;
#pragma unroll
            for (int i = 0; i < 2; ++i) {
                int r = w * 32 + i * 16 + (lane & 15);
                int kk = kbase ^ ((r & 7) << 3);
                a[i] = *(bf16x8*)&As[r * 64 + kk];
            }
#pragma unroll
            for (int jj = 0; jj < 8; ++jj) {
                int o = jj * 16 + (lane & 15);
                int kk = kbase ^ ((o & 7) << 3);
                b[jj] = *(bf16x8*)&Bs[o * 64 + kk];
            }
#pragma unroll
            for (int i = 0; i < 2; ++i)
#pragma unroll
                for (int jj = 0; jj < 8; ++jj)
                    acc[i][jj] = __builtin_amdgcn_mfma_f32_16x16x32_bf16(a[i], b[jj], acc[i][jj], 0, 0, 0);
        }
    }

#pragma unroll
    for (int i = 0; i < 2; ++i) {
        int mbase = w * 32 + i * 16 + (lane >> 4) * 4;
#pragma unroll
        for (int q = 0; q < 4; ++q) {
            int m = mbase + q;
            int gr = gbase + row0 + m;
            if (row0 + m < rows && gr < N) {
#pragma unroll
                for (int jj = 0; jj < 8; ++jj) {
                    int n = jj * 16 + (lane & 15);
                    out[(size_t)gr * F + n] = fmaxf(acc[i][jj][q], 0.f);
                }
            }
        }
    }
}

extern "C" void kernel_launch(void* const* d_in, const int* in_sizes, int n_in,
                              void* d_out, int out_size, void* d_ws, size_t ws_size,
                              hipStream_t stream) {
    const float* x  = (const float*)d_in[0];
    const float* Wb = (const float*)d_in[1];
    const float* Wc = (const float*)d_in[2];
    const float* ev = (const float*)d_in[3];
    const int*   es = (const int*)d_in[4];
    const int*   ed = (const int*)d_in[5];
    float* out = (float*)d_out;

    const int N = in_sizes[0] / F;
    const int E = in_sizes[3] / NR;

    char* p = (char*)d_ws;
    auto alloc = [&](size_t bytes) -> char* {
        char* q = p;
        p += (bytes + 255) & ~(size_t)255;
        return q;
    };
    int2* payload          = (int2*)alloc((size_t)NR * E * 8);
    int* cnt               = (int*)alloc((size_t)N * 4);
    int* offs              = (int*)alloc((size_t)(N + 1) * 4);
    int* curs              = (int*)alloc((size_t)N * 4);
    unsigned short* Bt     = (unsigned short*)alloc((size_t)F * NB * F * 2);

    const size_t rank_sz = (size_t)NR * E * 2;
    const size_t xb_sz   = (size_t)N * F * 2;
    const size_t mix_min = 128 * 512 * 2;

    size_t used = (size_t)(p - (char*)d_ws);
    size_t rem = ws_size > used ? ws_size - used : 0;

    bool use_rank = rem >= rank_sz + mix_min + (4u << 20);
    unsigned short* rank = nullptr;
    if (use_rank) {
        rank = (unsigned short*)alloc(rank_sz);
        rem = ws_size - (size_t)(p - (char*)d_ws);
    }
    bool use_xb = rem >= xb_sz + mix_min + (1u << 20);
    const void* xsrc = (const void*)x;
    if (use_xb) {
        xsrc = (const void*)alloc(xb_sz);
        rem = ws_size - (size_t)(p - (char*)d_ws);
    }
    size_t mix_rows = (rem / (512 * 2)) & ~(size_t)127;
    int chunk = (int)(mix_rows < 128 ? 128 : (mix_rows > (size_t)N ? (size_t)((N + 127) & ~127) : mix_rows));
    unsigned short* mixbuf = (unsigned short*)p;

    hipMemsetAsync(cnt, 0, (size_t)N * 4, stream);
    if (use_xb)
        cvt_x_kernel<<<(N * F / 8 + 255) / 256, 256, 0, stream>>>((const float4*)x, (uint4*)xsrc, N * F / 8);
    cvt_w_kernel<<<(F * NB * F + 255) / 256, 256, 0, stream>>>(Wb, Bt);

    dim3 eg((E + 255) / 256, NR);
    if (use_rank) hist_kernel<true><<<eg, 256, 0, stream>>>(ed, cnt, rank, E);
    else          hist_kernel<false><<<eg, 256, 0, stream>>>(ed, cnt, nullptr, E);

    scan_kernel<<<1, 1024, 0, stream>>>(cnt, offs, use_rank ? nullptr : curs, N);

    if (use_rank) fill_kernel<true><<<eg, 256, 0, stream>>>(es, ev, ed, offs, rank, nullptr, payload, E);
    else          fill_kernel<false><<<eg, 256, 0, stream>>>(es, ev, ed, offs, nullptr, curs, payload, E);

    for (int c0 = 0; c0 < N; c0 += chunk) {
        int crows = min(chunk, N - c0);
        if (use_xb)
            accum_kernel<true><<<(crows + 3) / 4, 256, 0, stream>>>(xsrc, payload, offs, Wc,
                                                                    (unsigned*)mixbuf, c0, c0 + crows);
        else
            accum_kernel<false><<<(crows + 3) / 4, 256, 0, stream>>>((const void*)x, payload, offs, Wc,
                                                                     (unsigned*)mixbuf, c0, c0 + crows);
        gemm_mfma<<<(crows + 127) / 128, 256, 0, stream>>>(mixbuf, Bt, out, crows, c0, N);
    }
}

// Round 4
// 485.095 us; speedup vs baseline: 14.6920x; 1.1130x over previous
//
#include <hip/hip_runtime.h>

#define F 128
#define NB 4
#define NR 8
#define CAP 160

typedef __attribute__((ext_vector_type(8))) short bf16x8;
typedef __attribute__((ext_vector_type(4))) float f32x4;
typedef __attribute__((ext_vector_type(2))) float f32x2;

__device__ __forceinline__ unsigned f2bf(float f) {  // RNE f32->bf16
    unsigned u = __float_as_uint(f);
    return (u + 0x7FFFu + ((u >> 16) & 1u)) >> 16;
}
__device__ __forceinline__ unsigned f2bf2(float lo, float hi) {
    return f2bf(lo) | (f2bf(hi) << 16);
}

// x f32 [N*128] -> bf16, 8 elems/thread
__global__ void cvt_x_kernel(const float4* __restrict__ x4, uint4* __restrict__ xb, int total8) {
    int i = blockIdx.x * blockDim.x + threadIdx.x;
    if (i >= total8) return;
    float4 a = x4[(size_t)i * 2], b = x4[(size_t)i * 2 + 1];
    xb[i] = make_uint4(f2bf2(a.x, a.y), f2bf2(a.z, a.w), f2bf2(b.x, b.y), f2bf2(b.z, b.w));
}

// Bt[o][b*128+k] = bf16(W_basis[b][k][o]) : [128][512]
__global__ void cvt_w_kernel(const float* __restrict__ Wb, unsigned short* __restrict__ Bt) {
    int t = blockIdx.x * blockDim.x + threadIdx.x;
    if (t >= F * NB * F) return;
    int o = t >> 9, bk = t & 511, b = bk >> 7, k = bk & 127;
    Bt[t] = (unsigned short)f2bf(Wb[((size_t)b * F + k) * F + o]);
}

// one pass: count dst degree AND place (src|rel, val) at payload[d*CAP + rank].
__global__ void hist_fill_kernel(const int* __restrict__ es, const float* __restrict__ ev,
                                 const int* __restrict__ ed, int* __restrict__ cnt,
                                 int2* __restrict__ payload, int E) {
    int e = blockIdx.x * blockDim.x + threadIdx.x;
    if (e >= E) return;
    int r = blockIdx.y;
    size_t idx = (size_t)r * E + e;
    int d = ed[idx];
    int s = es[idx];
    float v = ev[idx];
    int rk = atomicAdd(&cnt[d], 1);
    if (rk < CAP)
        payload[(size_t)d * CAP + rk] = make_int2(s | (r << 24), __float_as_int(v));
}

// one wave per dst: gather bf16 x rows, accumulate 4 basis-weighted sums
// (f32x2 packed math), write mix[d][b*128 + lane*2 .. +1] as packed bf16.
__global__ __launch_bounds__(256) void accum_kernel(const unsigned* __restrict__ xb,
                                                    const int2* __restrict__ payload,
                                                    const int* __restrict__ cnt,
                                                    const float* __restrict__ comp,
                                                    unsigned* __restrict__ mix,
                                                    int c0, int c1) {
    __shared__ float4 scomp[NR];
    if (threadIdx.x < NR) scomp[threadIdx.x] = ((const float4*)comp)[threadIdx.x];
    __syncthreads();
    int wave = threadIdx.x >> 6, lane = threadIdx.x & 63;
    int d = c0 + blockIdx.x * 4 + wave;
    if (d >= c1) return;
    size_t jb = (size_t)d * CAP;
    int deg = min(cnt[d], CAP);
    f32x2 acc0 = {0.f, 0.f}, acc1 = {0.f, 0.f}, acc2 = {0.f, 0.f}, acc3 = {0.f, 0.f};
    int j = 0;
    for (; j + 4 <= deg; j += 4) {
        int4 ma = *(const int4*)&payload[jb + j];       // edges j, j+1
        int4 mb = *(const int4*)&payload[jb + j + 2];   // edges j+2, j+3
        unsigned p0 = (unsigned)ma.x, p1 = (unsigned)ma.z;
        unsigned p2 = (unsigned)mb.x, p3 = (unsigned)mb.z;
        unsigned g0 = xb[(size_t)(p0 & 0xFFFFFFu) * 64 + lane];
        unsigned g1 = xb[(size_t)(p1 & 0xFFFFFFu) * 64 + lane];
        unsigned g2 = xb[(size_t)(p2 & 0xFFFFFFu) * 64 + lane];
        unsigned g3 = xb[(size_t)(p3 & 0xFFFFFFu) * 64 + lane];
        float4 cw;
        float v;
        f32x2 xv;
        v = __int_as_float(ma.y); cw = scomp[p0 >> 24];
        xv = (f32x2){__uint_as_float(g0 << 16), __uint_as_float(g0 & 0xFFFF0000u)};
        acc0 += xv * (v * cw.x); acc1 += xv * (v * cw.y);
        acc2 += xv * (v * cw.z); acc3 += xv * (v * cw.w);
        v = __int_as_float(ma.w); cw = scomp[p1 >> 24];
        xv = (f32x2){__uint_as_float(g1 << 16), __uint_as_float(g1 & 0xFFFF0000u)};
        acc0 += xv * (v * cw.x); acc1 += xv * (v * cw.y);
        acc2 += xv * (v * cw.z); acc3 += xv * (v * cw.w);
        v = __int_as_float(mb.y); cw = scomp[p2 >> 24];
        xv = (f32x2){__uint_as_float(g2 << 16), __uint_as_float(g2 & 0xFFFF0000u)};
        acc0 += xv * (v * cw.x); acc1 += xv * (v * cw.y);
        acc2 += xv * (v * cw.z); acc3 += xv * (v * cw.w);
        v = __int_as_float(mb.w); cw = scomp[p3 >> 24];
        xv = (f32x2){__uint_as_float(g3 << 16), __uint_as_float(g3 & 0xFFFF0000u)};
        acc0 += xv * (v * cw.x); acc1 += xv * (v * cw.y);
        acc2 += xv * (v * cw.z); acc3 += xv * (v * cw.w);
    }
    for (; j < deg; ++j) {
        int2 m = payload[jb + j];
        unsigned pp = (unsigned)m.x;
        unsigned g = xb[(size_t)(pp & 0xFFFFFFu) * 64 + lane];
        float v = __int_as_float(m.y);
        float4 cw = scomp[pp >> 24];
        f32x2 xv = (f32x2){__uint_as_float(g << 16), __uint_as_float(g & 0xFFFF0000u)};
        acc0 += xv * (v * cw.x); acc1 += xv * (v * cw.y);
        acc2 += xv * (v * cw.z); acc3 += xv * (v * cw.w);
    }
    unsigned* mrow = mix + (size_t)(d - c0) * 256 + lane;
    mrow[0]   = f2bf2(acc0.x, acc0.y);
    mrow[64]  = f2bf2(acc1.x, acc1.y);
    mrow[128] = f2bf2(acc2.x, acc2.y);
    mrow[192] = f2bf2(acc3.x, acc3.y);
}

// out[gbase+row][o] = relu( sum_K mix[row][K] * Bt[o][K] ), K=512.
// 4 waves, tile 128x128, BK=64, XOR-swizzled LDS, MFMA 16x16x32 bf16.
__global__ __launch_bounds__(256) void gemm_mfma(const unsigned short* __restrict__ mix,
                                                 const unsigned short* __restrict__ Bt,
                                                 float* __restrict__ out,
                                                 int rows, int gbase, int N) {
    __shared__ unsigned short As[128 * 64];
    __shared__ unsigned short Bs[128 * 64];
    const int t = threadIdx.x;
    const int row0 = blockIdx.x * 128;
    const int w = t >> 6, lane = t & 63;
    f32x4 acc[2][8] = {};

    for (int kt = 0; kt < 8; ++kt) {
        __syncthreads();
        for (int u = t; u < 1024; u += 256) {
            int r = u >> 3, c = u & 7;
            int k8 = c * 8;
            int ks = k8 ^ ((r & 7) << 3);
            uint4 av = make_uint4(0, 0, 0, 0);
            if (row0 + r < rows) av = *(const uint4*)&mix[(size_t)(row0 + r) * 512 + kt * 64 + k8];
            *(uint4*)&As[r * 64 + ks] = av;
            uint4 bv = *(const uint4*)&Bt[(size_t)r * 512 + kt * 64 + k8];
            *(uint4*)&Bs[r * 64 + ks] = bv;
        }
        __syncthreads();
#pragma unroll
        for (int ks = 0; ks < 2; ++ks) {
            bf16x8 a[2], b[8];
            const int kbase = ks * 32 + (lane >> 4) * 8;
#pragma unroll
            for (int i = 0; i < 2; ++i) {
                int r = w * 32 + i * 16 + (lane & 15);
                int kk = kbase ^ ((r & 7) << 3);
                a[i] = *(bf16x8*)&As[r * 64 + kk];
            }
#pragma unroll
            for (int jj = 0; jj < 8; ++jj) {
                int o = jj * 16 + (lane & 15);
                int kk = kbase ^ ((o & 7) << 3);
                b[jj] = *(bf16x8*)&Bs[o * 64 + kk];
            }
#pragma unroll
            for (int i = 0; i < 2; ++i)
#pragma unroll
                for (int jj = 0; jj < 8; ++jj)
                    acc[i][jj] = __builtin_amdgcn_mfma_f32_16x16x32_bf16(a[i], b[jj], acc[i][jj], 0, 0, 0);
        }
    }

#pragma unroll
    for (int i = 0; i < 2; ++i) {
        int mbase = w * 32 + i * 16 + (lane >> 4) * 4;
#pragma unroll
        for (int q = 0; q < 4; ++q) {
            int m = mbase + q;
            int gr = gbase + row0 + m;
            if (row0 + m < rows && gr < N) {
#pragma unroll
                for (int jj = 0; jj < 8; ++jj) {
                    int n = jj * 16 + (lane & 15);
                    out[(size_t)gr * F + n] = fmaxf(acc[i][jj][q], 0.f);
                }
            }
        }
    }
}

extern "C" void kernel_launch(void* const* d_in, const int* in_sizes, int n_in,
                              void* d_out, int out_size, void* d_ws, size_t ws_size,
                              hipStream_t stream) {
    const float* x  = (const float*)d_in[0];
    const float* Wb = (const float*)d_in[1];
    const float* Wc = (const float*)d_in[2];
    const float* ev = (const float*)d_in[3];
    const int*   es = (const int*)d_in[4];
    const int*   ed = (const int*)d_in[5];
    float* out = (float*)d_out;

    const int N = in_sizes[0] / F;
    const int E = in_sizes[3] / NR;

    char* p = (char*)d_ws;
    auto alloc = [&](size_t bytes) -> char* {
        char* q = p;
        p += (bytes + 255) & ~(size_t)255;
        return q;
    };
    int2* payload      = (int2*)alloc((size_t)N * CAP * 8);          // 64 MB
    int* cnt           = (int*)alloc((size_t)N * 4);                 // 0.2 MB
    unsigned short* Bt = (unsigned short*)alloc((size_t)F * NB * F * 2);
    unsigned* xb       = (unsigned*)alloc((size_t)N * F * 2);        // 12.8 MB

    size_t used = (size_t)(p - (char*)d_ws);
    size_t rem = ws_size > used ? ws_size - used : (size_t)(128 * 1024);
    size_t mix_rows = (rem / (512 * 2)) & ~(size_t)127;
    int chunk = (int)(mix_rows < 128 ? 128
                      : (mix_rows > (size_t)N ? (size_t)((N + 127) & ~(size_t)127) : mix_rows));
    unsigned short* mixbuf = (unsigned short*)p;

    hipMemsetAsync(cnt, 0, (size_t)N * 4, stream);
    cvt_x_kernel<<<(N * F / 8 + 255) / 256, 256, 0, stream>>>((const float4*)x, (uint4*)xb, N * F / 8);
    cvt_w_kernel<<<(F * NB * F + 255) / 256, 256, 0, stream>>>(Wb, Bt);

    dim3 eg((E + 255) / 256, NR);
    hist_fill_kernel<<<eg, 256, 0, stream>>>(es, ev, ed, cnt, payload, E);

    for (int c0 = 0; c0 < N; c0 += chunk) {
        int crows = min(chunk, N - c0);
        accum_kernel<<<(crows + 3) / 4, 256, 0, stream>>>(xb, payload, cnt, Wc,
                                                          (unsigned*)mixbuf, c0, c0 + crows);
        gemm_mfma<<<(crows + 127) / 128, 256, 0, stream>>>(mixbuf, Bt, out, crows, c0, N);
    }
}